// Round 1
// 225.658 us; speedup vs baseline: 1.0765x; 1.0765x over previous
//
#include <hip/hip_runtime.h>
#include <hip/hip_fp16.h>
#include <math.h>

// GAT layer: N=50000, E=800000, IN=256, H=4, C=32.
// R10: fuse wedge into agg (f32 weights computed inline from packed
// arw[n][h]={ar,rdenom}); agg reworked to 32 lanes/node with 8B ushort4
// h-gathers, cooperative adj preload + __shfl broadcast (no per-edge
// adj-load dependency), 4-edge unroll for deep MLP. k_wedge/wD deleted.
// GEMM (R9 barrier-free-K MFMA) and CSR build (R8 bucketed) unchanged.

#define NH 4
#define CH 32
#define HC 128
#define IND 256
#define NEG_SLOPE 0.2f
#define CSH 8           // coarse bucket = 256 nodes
#define NCB_MAX 256
#define CHUNK 4096

typedef __attribute__((ext_vector_type(8))) short bf16x8;
typedef __attribute__((ext_vector_type(16))) float f32x16;

__device__ __forceinline__ unsigned short f2bf(float f) {
    unsigned int u = __float_as_uint(f);
    unsigned int r = (u + 0x7FFFu + ((u >> 16) & 1u)) >> 16;   // RNE
    return (unsigned short)r;
}
__device__ __forceinline__ float bf2f(unsigned short s) {
    return __uint_as_float(((unsigned int)s) << 16);
}

__global__ __launch_bounds__(256) void k_init0(int* __restrict__ histS,
                                               int* __restrict__ histD, int ncb) {
    int t = threadIdx.x;
    if (t < ncb) { histS[t] = 0; histD[t] = 0; }
}

// WT_bf[c][k] = bf16(W[k][c]) — one-time transpose+convert.
__global__ __launch_bounds__(256) void k_wprep(const float* __restrict__ W,
                                               unsigned short* __restrict__ WT_bf) {
    int t = blockIdx.x * 256 + threadIdx.x;
    if (t >= IND * HC) return;
    int c = t >> 8;
    int k = t & 255;
    WT_bf[t] = f2bf(W[k * HC + c]);
}

// h_bf = bf16(x @ W) via 32x32x16 MFMA, barrier-free K-loop.
// Block: 256 thr = 4 waves x 32 rows = 128 rows; 4 col-tiles of 32.
// A-layout: lane holds A[m=lane&31][k=(lane>>5)*8+j]; B analogous;
// C/D: col=lane&31, row=(reg&3)+8*(reg>>2)+4*(lane>>5)  [m74/m101].
__global__ __launch_bounds__(256) void k_gemm_mfma(const float* __restrict__ x,
                                                   const unsigned short* __restrict__ WT_bf,
                                                   const float* __restrict__ att,
                                                   unsigned short* __restrict__ h_bf,
                                                   float* __restrict__ al,
                                                   float* __restrict__ ar, int N) {
    __shared__ float cs[128 * 129];                    // 66048 B
    unsigned short* wsT = (unsigned short*)cs;         // [128][258] = 66048 B

    const int tid  = threadIdx.x;
    const int row0 = blockIdx.x * 128;
    const int wave = tid >> 6;
    const int lane = tid & 63;
    const int n32  = lane & 31;
    const int half = lane >> 5;

    // stage full W once: thread copies half a column (128 shorts, int4 x16)
    {
        int c  = tid >> 1;
        int kh = (tid & 1) * 128;
        const unsigned short* src = WT_bf + c * IND + kh;
        unsigned short* dst = wsT + c * 258 + kh;
#pragma unroll
        for (int j = 0; j < 128; j += 8)
            *(int4*)(dst + j) = *(const int4*)(src + j);
    }
    __syncthreads();

    const int row   = row0 + wave * 32 + n32;
    const bool valid = row < N;
    const float* xrow = x + (size_t)row * IND + half * 8;

    f32x16 acc[4];
#pragma unroll
    for (int t = 0; t < 4; t++)
#pragma unroll
        for (int r = 0; r < 16; r++) acc[t][r] = 0.0f;

    // 16 K-steps of 16; NO barriers inside.
#pragma unroll 4
    for (int s = 0; s < 16; s++) {
        float4 v0 = make_float4(0.f, 0.f, 0.f, 0.f);
        float4 v1 = v0;
        if (valid) {
            v0 = *(const float4*)(xrow + s * 16);
            v1 = *(const float4*)(xrow + s * 16 + 4);
        }
        bf16x8 a;
        a[0] = (short)f2bf(v0.x); a[1] = (short)f2bf(v0.y);
        a[2] = (short)f2bf(v0.z); a[3] = (short)f2bf(v0.w);
        a[4] = (short)f2bf(v1.x); a[5] = (short)f2bf(v1.y);
        a[6] = (short)f2bf(v1.z); a[7] = (short)f2bf(v1.w);
#pragma unroll
        for (int t = 0; t < 4; t++) {
            bf16x8 b = *(const bf16x8*)(wsT + (t * 32 + n32) * 258 + s * 16 + half * 8);
            acc[t] = __builtin_amdgcn_mfma_f32_32x32x16_bf16(a, b, acc[t], 0, 0, 0);
        }
    }
    __syncthreads();   // wsT dead; cs aliases it

    // C frags -> cs (129-f32 stride: banks = rl + col, 2-way max = free)
#pragma unroll
    for (int t = 0; t < 4; t++)
#pragma unroll
        for (int r = 0; r < 16; r++) {
            int rl = wave * 32 + (r & 3) + 8 * (r >> 2) + 4 * half;
            cs[rl * 129 + t * 32 + n32] = acc[t][r];
        }
    __syncthreads();

    // epilogue: thread -> (row_local = tid>>1, col-half = tid&1 -> heads 2h,2h+1)
    const int rl   = tid >> 1;
    const int chf  = tid & 1;
    const int orow = row0 + rl;
    if (orow < N) {
        const float* cr = cs + rl * 129 + chf * 64;
        unsigned short* hp = h_bf + (size_t)orow * HC + chf * 64;
#pragma unroll
        for (int c = 0; c < 64; c += 8) {
            ushort4 o0, o1;
            o0.x = f2bf(cr[c]);     o0.y = f2bf(cr[c + 1]);
            o0.z = f2bf(cr[c + 2]); o0.w = f2bf(cr[c + 3]);
            o1.x = f2bf(cr[c + 4]); o1.y = f2bf(cr[c + 5]);
            o1.z = f2bf(cr[c + 6]); o1.w = f2bf(cr[c + 7]);
            *(ushort4*)(hp + c) = o0;
            *(ushort4*)(hp + c + 4) = o1;
        }
        const int h0 = 2 * chf, h1 = 2 * chf + 1;
        const float* w0 = att + h0 * (2 * CH);
        const float* w1 = att + h1 * (2 * CH);
        float sl0 = 0.f, sr0 = 0.f, sl1 = 0.f, sr1 = 0.f;
#pragma unroll
        for (int c = 0; c < CH; c++) {
            float v0 = cr[c];
            float v1 = cr[CH + c];
            sl0 += v0 * w0[c];  sr0 += v0 * w0[CH + c];
            sl1 += v1 * w1[c];  sr1 += v1 * w1[CH + c];
        }
        al[orow * NH + h0] = sl0;  al[orow * NH + h1] = sl1;
        ar[orow * NH + h0] = sr0;  ar[orow * NH + h1] = sr1;
    }
}

// coarse histograms, LDS-staged.
__global__ __launch_bounds__(256) void k_hist(const int* __restrict__ ei,
                                              int* __restrict__ histS,
                                              int* __restrict__ histD,
                                              int E, int NE, int ncb) {
    __shared__ int hs[NCB_MAX], hd[NCB_MAX];
    hs[threadIdx.x] = 0; hd[threadIdx.x] = 0;
    __syncthreads();
    for (int t = blockIdx.x * 256 + threadIdx.x; t < NE; t += gridDim.x * 256) {
        int src, dst;
        if (t < E) { src = ei[t]; dst = ei[E + t]; }
        else       { src = dst = t - E; }
        atomicAdd(&hs[src >> CSH], 1);
        atomicAdd(&hd[dst >> CSH], 1);
    }
    __syncthreads();
    int i = threadIdx.x;
    if (i < ncb) {
        if (hs[i]) atomicAdd(&histS[i], hs[i]);
        if (hd[i]) atomicAdd(&histD[i], hd[i]);
    }
}

// one block: parallel exclusive scan over ncb buckets, both sides.
__global__ __launch_bounds__(256) void k_scanC(const int* __restrict__ histS,
                                               const int* __restrict__ histD,
                                               int* __restrict__ baseS,
                                               int* __restrict__ baseD,
                                               int* __restrict__ curS,
                                               int* __restrict__ curD,
                                               int* __restrict__ rowptrS,
                                               int* __restrict__ rowptrD,
                                               int ncb, int NE, int N) {
    __shared__ int sc[256];
    int tid = threadIdx.x;
    int v = (tid < ncb) ? histS[tid] : 0;
    sc[tid] = v;
    __syncthreads();
    for (int o = 1; o < 256; o <<= 1) {
        int t = (tid >= o) ? sc[tid - o] : 0;
        __syncthreads();
        sc[tid] += t;
        __syncthreads();
    }
    if (tid < ncb) { baseS[tid] = sc[tid] - v; curS[tid] = sc[tid] - v; }
    if (tid == 0) { baseS[ncb] = sc[255]; rowptrS[N] = NE; }
    __syncthreads();
    v = (tid < ncb) ? histD[tid] : 0;
    sc[tid] = v;
    __syncthreads();
    for (int o = 1; o < 256; o <<= 1) {
        int t = (tid >= o) ? sc[tid - o] : 0;
        __syncthreads();
        sc[tid] += t;
        __syncthreads();
    }
    if (tid < ncb) { baseD[tid] = sc[tid] - v; curD[tid] = sc[tid] - v; }
    if (tid == 0) { baseD[ncb] = sc[255]; rowptrD[N] = NE; }
}

// chunked scatter into coarse streams, LDS-binned (full-line appends).
__global__ __launch_bounds__(256) void k_scatterC(const int* __restrict__ ei,
                                                  int* __restrict__ gcurS,
                                                  int* __restrict__ gcurD,
                                                  unsigned int* __restrict__ recS,
                                                  unsigned int* __restrict__ recD,
                                                  int E, int NE, int ncb) {
    __shared__ unsigned int srt[CHUNK];          // 16 KB
    __shared__ int cnt[NCB_MAX], off[NCB_MAX], cur[NCB_MAX], gpos[NCB_MAX], sc[256];
    const int tid = threadIdx.x;
    const int t0  = blockIdx.x * CHUNK;
    const int m   = min(CHUNK, NE - t0);

    unsigned int myrec[CHUNK / 256];
    int nmy = 0;
    for (int i = tid; i < m; i += 256) {
        int t = t0 + i;
        int src, dst;
        if (t < E) { src = ei[t]; dst = ei[E + t]; }
        else       { src = dst = t - E; }
        myrec[nmy++] = (unsigned int)src | ((unsigned int)dst << 16);
    }

    for (int side = 0; side < 2; side++) {       // 0 = S (by src), 1 = D (by dst)
        cnt[tid] = 0;
        __syncthreads();
        int mybkt[CHUNK / 256];
        for (int k = 0; k < nmy; k++) {
            unsigned int r = myrec[k];
            int node = side ? (int)(r >> 16) : (int)(r & 0xFFFFu);
            mybkt[k] = node >> CSH;
            atomicAdd(&cnt[mybkt[k]], 1);
        }
        __syncthreads();
        int v = cnt[tid];
        sc[tid] = v;
        __syncthreads();
        for (int o = 1; o < 256; o <<= 1) {
            int t = (tid >= o) ? sc[tid - o] : 0;
            __syncthreads();
            sc[tid] += t;
            __syncthreads();
        }
        off[tid] = sc[tid] - v;
        cur[tid] = sc[tid] - v;
        __syncthreads();
        for (int k = 0; k < nmy; k++) {
            int p = atomicAdd(&cur[mybkt[k]], 1);
            srt[p] = myrec[k];
        }
        __syncthreads();
        int* gcur = side ? gcurD : gcurS;
        if (tid < ncb) {
            int c = cnt[tid];
            gpos[tid] = c ? atomicAdd(&gcur[tid], c) : 0;
        }
        __syncthreads();
        unsigned int* recX = side ? recD : recS;
        for (int i = tid; i < m; i += 256) {
            unsigned int r = srt[i];
            int node = side ? (int)(r >> 16) : (int)(r & 0xFFFFu);
            int cb = node >> CSH;
            recX[gpos[cb] + (i - off[cb])] = r;
        }
        __syncthreads();
    }
}

// block per (side, coarse bucket): node-level CSR inside private region.
__global__ __launch_bounds__(256) void k_rebin(const unsigned int* __restrict__ recS,
                                               const unsigned int* __restrict__ recD,
                                               const int* __restrict__ baseS,
                                               const int* __restrict__ baseD,
                                               unsigned short* __restrict__ adjS,
                                               unsigned short* __restrict__ adjD,
                                               int* __restrict__ rowptrS,
                                               int* __restrict__ rowptrD,
                                               int ncb, int N) {
    __shared__ int cnt[256], cur[256], sc[256];
    const int tid  = threadIdx.x;
    const int side = (blockIdx.x >= ncb) ? 1 : 0;
    const int cb   = side ? blockIdx.x - ncb : blockIdx.x;
    const unsigned int* rec = side ? recD : recS;
    const int* base = side ? baseD : baseS;
    const int b0 = base[cb], b1 = base[cb + 1];
    const int tot_rec = b1 - b0;

    cnt[tid] = 0;
    __syncthreads();
    for (int i = tid; i < tot_rec; i += 256) {
        unsigned int r = rec[b0 + i];
        int node = side ? (int)(r >> 16) : (int)(r & 0xFFFFu);
        atomicAdd(&cnt[node & 255], 1);
    }
    __syncthreads();
    int v = cnt[tid];
    sc[tid] = v;
    __syncthreads();
    for (int o = 1; o < 256; o <<= 1) {
        int t = (tid >= o) ? sc[tid - o] : 0;
        __syncthreads();
        sc[tid] += t;
        __syncthreads();
    }
    int ex = sc[tid] - v;
    int node_g = (cb << CSH) + tid;
    int* rowptr = side ? rowptrD : rowptrS;
    if (node_g < N) rowptr[node_g] = b0 + ex;
    cur[tid] = ex;
    __syncthreads();
    unsigned short* adj = side ? adjD : adjS;
    for (int i = tid; i < tot_rec; i += 256) {
        unsigned int r = rec[b0 + i];
        int node = side ? (int)(r >> 16) : (int)(r & 0xFFFFu);
        unsigned short other = side ? (unsigned short)(r & 0xFFFFu)
                                    : (unsigned short)(r >> 16);
        int p = atomicAdd(&cur[node & 255], 1);
        adj[b0 + p] = other;
    }
}

// rdenom[n][h] = 1/(sum over out-edges exp(leaky(al[dst]+ar[n])) + 1e-16)
// Also emits packed arw[n][h] = {ar, rdenom} (float2) for the fused agg.
__global__ __launch_bounds__(256) void k_denom(const int* __restrict__ rowptrS,
                                               const unsigned short* __restrict__ adjS,
                                               const float* __restrict__ al,
                                               const float* __restrict__ ar,
                                               float* __restrict__ arw, int N) {
    int n = blockIdx.x * 256 + threadIdx.x;
    if (n >= N) return;
    int beg = rowptrS[n], end = rowptrS[n + 1];
    float4 arv = *(const float4*)(ar + n * NH);
    float s0 = 0.f, s1 = 0.f, s2 = 0.f, s3 = 0.f;
    int i = beg;
    for (; i + 2 <= end; i += 2) {
        int d0 = adjS[i], d1 = adjS[i + 1];
        float4 av0 = *(const float4*)(al + d0 * NH);
        float4 av1 = *(const float4*)(al + d1 * NH);
        float a0 = av0.x + arv.x, a1 = av0.y + arv.y;
        float a2 = av0.z + arv.z, a3 = av0.w + arv.w;
        float c0 = av1.x + arv.x, c1 = av1.y + arv.y;
        float c2 = av1.z + arv.z, c3 = av1.w + arv.w;
        a0 = (a0 > 0.f) ? a0 : NEG_SLOPE * a0;
        a1 = (a1 > 0.f) ? a1 : NEG_SLOPE * a1;
        a2 = (a2 > 0.f) ? a2 : NEG_SLOPE * a2;
        a3 = (a3 > 0.f) ? a3 : NEG_SLOPE * a3;
        c0 = (c0 > 0.f) ? c0 : NEG_SLOPE * c0;
        c1 = (c1 > 0.f) ? c1 : NEG_SLOPE * c1;
        c2 = (c2 > 0.f) ? c2 : NEG_SLOPE * c2;
        c3 = (c3 > 0.f) ? c3 : NEG_SLOPE * c3;
        s0 += __expf(a0) + __expf(c0);
        s1 += __expf(a1) + __expf(c1);
        s2 += __expf(a2) + __expf(c2);
        s3 += __expf(a3) + __expf(c3);
    }
    if (i < end) {
        int d0 = adjS[i];
        float4 av = *(const float4*)(al + d0 * NH);
        float a0 = av.x + arv.x, a1 = av.y + arv.y;
        float a2 = av.z + arv.z, a3 = av.w + arv.w;
        a0 = (a0 > 0.f) ? a0 : NEG_SLOPE * a0;
        a1 = (a1 > 0.f) ? a1 : NEG_SLOPE * a1;
        a2 = (a2 > 0.f) ? a2 : NEG_SLOPE * a2;
        a3 = (a3 > 0.f) ? a3 : NEG_SLOPE * a3;
        s0 += __expf(a0); s1 += __expf(a1);
        s2 += __expf(a2); s3 += __expf(a3);
    }
    float r0 = 1.0f / (s0 + 1e-16f);
    float r1 = 1.0f / (s1 + 1e-16f);
    float r2 = 1.0f / (s2 + 1e-16f);
    float r3 = 1.0f / (s3 + 1e-16f);
    // interleave: arw[n*8 + 2h] = ar_h, arw[n*8 + 2h + 1] = rdenom_h
    float4 p0 = make_float4(arv.x, r0, arv.y, r1);
    float4 p1 = make_float4(arv.z, r2, arv.w, r3);
    *(float4*)(arw + (size_t)n * 8)     = p0;
    *(float4*)(arw + (size_t)n * 8 + 4) = p1;
}

// Fused weight+aggregate. 8 nodes/block, 32 lanes/node, 4 channels/lane
// (ushort4 = 8B gathers). adj preloaded 32-at-a-time (one coalesced 2B
// load) and broadcast via __shfl -> no adj-load in the dependent chain.
// Weight w = exp(leaky(al[n]+ar[s]))*rdenom[s] from one packed 8B arw
// load per edge (L2-hot, 1.6MB). 4-edge unroll = 4x(8B+8B) in flight.
__global__ __launch_bounds__(256) void k_agg(const int* __restrict__ rowptrD,
                                             const unsigned short* __restrict__ adjD,
                                             const float* __restrict__ al,
                                             const float* __restrict__ arw,
                                             const unsigned short* __restrict__ h_bf,
                                             const float* __restrict__ bias,
                                             float* __restrict__ out, int N) {
    const int g = threadIdx.x >> 5;
    const int n = blockIdx.x * 8 + g;
    if (n >= N) return;
    const int l  = threadIdx.x & 31;
    const int c0 = l * 4;            // 4 contiguous channels
    const int hh = l >> 3;           // head of this lane's channels
    const int beg = rowptrD[n], end = rowptrD[n + 1];
    const float alv = al[n * NH + hh];

    float a0 = 0.f, a1 = 0.f, a2 = 0.f, a3 = 0.f;

    for (int base = beg; base < end; base += 32) {
        int idx = base + l;
        int av  = (idx < end) ? (int)adjD[idx] : 0;   // coop preload (64B/group)
        int cnt = min(32, end - base);
        int e = 0;
        for (; e + 4 <= cnt; e += 4) {
            int s0 = __shfl(av, e,     32);
            int s1 = __shfl(av, e + 1, 32);
            int s2 = __shfl(av, e + 2, 32);
            int s3 = __shfl(av, e + 3, 32);
            ushort4 u0 = *(const ushort4*)(h_bf + (size_t)s0 * HC + c0);
            ushort4 u1 = *(const ushort4*)(h_bf + (size_t)s1 * HC + c0);
            ushort4 u2 = *(const ushort4*)(h_bf + (size_t)s2 * HC + c0);
            ushort4 u3 = *(const ushort4*)(h_bf + (size_t)s3 * HC + c0);
            float2 p0 = *(const float2*)(arw + (size_t)s0 * 8 + hh * 2);
            float2 p1 = *(const float2*)(arw + (size_t)s1 * 8 + hh * 2);
            float2 p2 = *(const float2*)(arw + (size_t)s2 * 8 + hh * 2);
            float2 p3 = *(const float2*)(arw + (size_t)s3 * 8 + hh * 2);
            float t0 = alv + p0.x; t0 = (t0 > 0.f) ? t0 : NEG_SLOPE * t0;
            float t1 = alv + p1.x; t1 = (t1 > 0.f) ? t1 : NEG_SLOPE * t1;
            float t2 = alv + p2.x; t2 = (t2 > 0.f) ? t2 : NEG_SLOPE * t2;
            float t3 = alv + p3.x; t3 = (t3 > 0.f) ? t3 : NEG_SLOPE * t3;
            float w0 = __expf(t0) * p0.y;
            float w1 = __expf(t1) * p1.y;
            float w2 = __expf(t2) * p2.y;
            float w3 = __expf(t3) * p3.y;
            a0 += bf2f(u0.x) * w0; a1 += bf2f(u0.y) * w0;
            a2 += bf2f(u0.z) * w0; a3 += bf2f(u0.w) * w0;
            a0 += bf2f(u1.x) * w1; a1 += bf2f(u1.y) * w1;
            a2 += bf2f(u1.z) * w1; a3 += bf2f(u1.w) * w1;
            a0 += bf2f(u2.x) * w2; a1 += bf2f(u2.y) * w2;
            a2 += bf2f(u2.z) * w2; a3 += bf2f(u2.w) * w2;
            a0 += bf2f(u3.x) * w3; a1 += bf2f(u3.y) * w3;
            a2 += bf2f(u3.z) * w3; a3 += bf2f(u3.w) * w3;
        }
        for (; e < cnt; e++) {
            int s0 = __shfl(av, e, 32);
            ushort4 u0 = *(const ushort4*)(h_bf + (size_t)s0 * HC + c0);
            float2 p0 = *(const float2*)(arw + (size_t)s0 * 8 + hh * 2);
            float t0 = alv + p0.x; t0 = (t0 > 0.f) ? t0 : NEG_SLOPE * t0;
            float w0 = __expf(t0) * p0.y;
            a0 += bf2f(u0.x) * w0; a1 += bf2f(u0.y) * w0;
            a2 += bf2f(u0.z) * w0; a3 += bf2f(u0.w) * w0;
        }
    }
    float4 b4 = *(const float4*)(bias + c0);
    *(float4*)(out + (size_t)n * HC + c0) =
        make_float4(a0 + b4.x, a1 + b4.y, a2 + b4.z, a3 + b4.w);
}

extern "C" void kernel_launch(void* const* d_in, const int* in_sizes, int n_in,
                              void* d_out, int out_size, void* d_ws, size_t ws_size,
                              hipStream_t stream) {
    const float* x    = (const float*)d_in[0];
    const float* W    = (const float*)d_in[1];
    const float* att  = (const float*)d_in[2];
    const float* bias = (const float*)d_in[3];
    const int*   ei   = (const int*)d_in[4];

    const int N  = in_sizes[0] / IND;     // 50000
    const int E  = in_sizes[4] / 2;       // 800000
    const int NE = E + N;
    const int ncb = (N + (1 << CSH) - 1) >> CSH;   // 196
    float* out = (float*)d_out;
    const int nodeTot = N * NH;

    // ws layout
    unsigned short* h_bf  = (unsigned short*)d_ws;             // N*128 u16 = 12.8MB
    unsigned short* WT_bf = h_bf + (size_t)N * HC;             // 32K u16
    float* al      = (float*)(WT_bf + IND * HC);               // N*4 f32
    float* ar      = al + nodeTot;                             // N*4
    float* rdenom  = ar + nodeTot;                             // N*4 (unused, layout keep)
    unsigned int* recS = (unsigned int*)(rdenom + nodeTot);    // NE u32
    unsigned int* recD = recS + NE;                            // NE u32
    unsigned short* adjS = (unsigned short*)(recD + NE);       // NE u16
    unsigned short* adjD = adjS + NE;                          // NE u16
    unsigned short* wD   = adjD + NE + (NE & 1);               // (unused, layout keep)
    int* rowptrS = (int*)(wD + (size_t)NE * NH);               // N+1
    int* rowptrD = rowptrS + (N + 2);                          // N+1
    int* histS   = rowptrD + (N + 2);                          // ncb
    int* histD   = histS + NCB_MAX;                            // ncb
    int* baseS   = histD + NCB_MAX;                            // ncb+1
    int* baseD   = baseS + (NCB_MAX + 1);                      // ncb+1
    int* curS    = baseD + (NCB_MAX + 1);                      // ncb
    int* curD    = curS + NCB_MAX;                             // ncb
    // packed {ar, rdenom} per (node, head): N*8 f32 = 1.6MB, 256B-aligned
    float* arw = (float*)((((uintptr_t)(curD + NCB_MAX)) + 255) & ~(uintptr_t)255);

    k_init0<<<1, 256, 0, stream>>>(histS, histD, ncb);
    k_wprep<<<(IND * HC + 255) / 256, 256, 0, stream>>>(W, WT_bf);
    k_gemm_mfma<<<(N + 127) / 128, 256, 0, stream>>>(x, WT_bf, att, h_bf, al, ar, N);
    k_hist<<<256, 256, 0, stream>>>(ei, histS, histD, E, NE, ncb);
    k_scanC<<<1, 256, 0, stream>>>(histS, histD, baseS, baseD, curS, curD,
                                   rowptrS, rowptrD, ncb, NE, N);
    k_scatterC<<<(NE + CHUNK - 1) / CHUNK, 256, 0, stream>>>(ei, curS, curD,
                                                             recS, recD, E, NE, ncb);
    k_rebin<<<2 * ncb, 256, 0, stream>>>(recS, recD, baseS, baseD, adjS, adjD,
                                         rowptrS, rowptrD, ncb, N);
    k_denom<<<(N + 255) / 256, 256, 0, stream>>>(rowptrS, adjS, al, ar, arw, N);
    k_agg<<<(N + 7) / 8, 256, 0, stream>>>(rowptrD, adjD, al, arw, h_bf, bias, out, N);
}